// Round 3
// baseline (479.440 us; speedup 1.0000x reference)
//
#include <hip/hip_runtime.h>
#include <math.h>

// Problem constants
#define N_ROWS   131072      // 32*64*64 pixels
#define DIM      64          // embedding dim
#define KCODES   1024        // codebook entries
#define HWSZ     4096        // 64*64
#define CHW      262144      // 64*64*64 (per-batch NCHW stride)
#define OUT_ELEMS 8388608    // 32*64*64*64
#define BLOCK    256
#define NBLOCKS  (N_ROWS / BLOCK)   // 512

// ---------------------------------------------------------------------------
// numpy pairwise sum of squares, n=64 (8-accumulator block, scalar order).
// Replicates np.sum(v**2, axis=-1) bit-exactly for 64 contiguous fp32:
//   r[j] = v[j]^2;  r[j] += v[8i+j]^2;  res = ((r0+r1)+(r2+r3))+((r4+r5)+(r6+r7))
// contract(off): keep mul and add as separate roundings (no fma fusion).
// ---------------------------------------------------------------------------
__device__ __forceinline__ float np_sumsq64(const float* v) {
#pragma clang fp contract(off)
    float r[8];
#pragma unroll
    for (int j = 0; j < 8; ++j) {
        float p = v[j] * v[j];
        r[j] = p;
    }
#pragma unroll
    for (int i = 8; i < 64; i += 8) {
#pragma unroll
        for (int j = 0; j < 8; ++j) {
            float p = v[i + j] * v[i + j];
            r[j] = r[j] + p;
        }
    }
    float s01 = r[0] + r[1];
    float s23 = r[2] + r[3];
    float s45 = r[4] + r[5];
    float s67 = r[6] + r[7];
    float l = s01 + s23;
    float h = s45 + s67;
    return l + h;
}

// ---------------------------------------------------------------------------
// Kernel 0: per-code ||w_k||^2 with numpy-pairwise semantics -> ws[0..1023]
// ---------------------------------------------------------------------------
__global__ __launch_bounds__(256) void vq_wsum(const float* __restrict__ w,
                                               float* __restrict__ wsum) {
    int k = blockIdx.x * blockDim.x + threadIdx.x;   // grid = 4*256 = 1024
    const float* wr = w + k * DIM;
    float wv[DIM];
#pragma unroll
    for (int d = 0; d < DIM; ++d) wv[d] = wr[d];
    wsum[k] = np_sumsq64(wv);
}

// ---------------------------------------------------------------------------
// Kernel 1: main VQ kernel. One thread per pixel/row.
//   Bit-exact emulation of the fp32 numpy reference:
//     a   = np_sumsq64(x)                       (pairwise, fp32)
//     c_k = sequential fmaf chain over d=0..63  (OpenBLAS sgemm k-loop)
//     d_k = fl( fl(a + b_k) - 2*c_k )           (elementwise fp32; 2*c exact)
//     argmin with strict < (first index wins, matches np.argmin)
// ---------------------------------------------------------------------------
__global__ __launch_bounds__(256) void vq_main(const float* __restrict__ inp,
                                               const float* __restrict__ weight,
                                               const float* __restrict__ wsum,
                                               float* __restrict__ out,
                                               float* __restrict__ idx_out,
                                               float* __restrict__ block_loss) {
    const int n  = blockIdx.x * BLOCK + threadIdx.x;   // grid exact: 512*256
    const int b  = n >> 12;            // n / 4096
    const int hw = n & 4095;           // n % 4096

    const float* xbase = inp + (size_t)b * CHW + hw;
    float x[DIM];
#pragma unroll
    for (int d = 0; d < DIM; ++d) x[d] = xbase[(size_t)d * HWSZ];

    const float a = np_sumsq64(x);

    float best  = 3.402823466e38f;
    int   bestk = 0;

    for (int k = 0; k < KCODES; ++k) {
        const float* wr = weight + k * DIM;   // block-uniform -> s_load path
        // OpenBLAS sgemm microkernel: single accumulator, sequential FMA in k
        float c = 0.f;
#pragma unroll
        for (int d = 0; d < DIM; ++d) c = __builtin_fmaf(x[d], wr[d], c);
        float s, dk;
        {
#pragma clang fp contract(off)
            s  = a + wsum[k];        // fl(a + b_k)
            dk = s - 2.0f * c;       // 2*c exact; one rounding
        }
        if (dk < best) { best = dk; bestk = k; }   // strict <: first index
    }

    // Epilogue: gather winning code row, write out (coalesced), loss partial.
    const float* wbest = weight + bestk * DIM;   // per-lane gather, L1/L2-hot
    float* obase = out + (size_t)b * CHW + hw;
    float  ls = 0.f;
#pragma unroll
    for (int c = 0; c < DIM; ++c) {
        const float wv = wbest[c];
        obase[(size_t)c * HWSZ] = wv;
        const float df = wv - x[c];
        ls = fmaf(df, df, ls);
    }
    idx_out[n] = (float)bestk;

    // Block reduction of loss partial (4 waves of 64)
    __shared__ float red[BLOCK / 64];
#pragma unroll
    for (int off = 32; off > 0; off >>= 1) ls += __shfl_down(ls, off, 64);
    const int lane = threadIdx.x & 63;
    const int wid  = threadIdx.x >> 6;
    if (lane == 0) red[wid] = ls;
    __syncthreads();
    if (threadIdx.x == 0)
        block_loss[blockIdx.x] = (red[0] + red[1]) + (red[2] + red[3]);
}

// ---------------------------------------------------------------------------
// Kernel 2: reduce 512 block partials -> loss scalar
//   loss = q + 0.25*e = 1.25 * mean((quantized - x)^2)
// ---------------------------------------------------------------------------
__global__ __launch_bounds__(256) void vq_loss_reduce(const float* __restrict__ bl,
                                                      float* __restrict__ loss_out) {
    double s = 0.0;
    for (int i = threadIdx.x; i < NBLOCKS; i += BLOCK) s += (double)bl[i];
    __shared__ double red[BLOCK / 64];
#pragma unroll
    for (int off = 32; off > 0; off >>= 1) s += __shfl_down(s, off, 64);
    const int lane = threadIdx.x & 63;
    const int wid  = threadIdx.x >> 6;
    if (lane == 0) red[wid] = s;
    __syncthreads();
    if (threadIdx.x == 0) {
        const double total = (red[0] + red[1]) + (red[2] + red[3]);
        loss_out[0] = (float)(1.25 * total / (double)OUT_ELEMS);
    }
}

// ---------------------------------------------------------------------------
extern "C" void kernel_launch(void* const* d_in, const int* in_sizes, int n_in,
                              void* d_out, int out_size, void* d_ws, size_t ws_size,
                              hipStream_t stream) {
    const float* inp    = (const float*)d_in[0];   // [32,64,64,64] NCHW fp32
    const float* weight = (const float*)d_in[1];   // [1024,64] fp32

    float* out_q    = (float*)d_out;                         // 8388608 elems
    float* out_loss = (float*)d_out + OUT_ELEMS;             // 1 elem
    float* out_idx  = (float*)d_out + OUT_ELEMS + 1;         // 131072 elems

    float* wsum       = (float*)d_ws;                        // 1024 floats
    float* block_loss = (float*)d_ws + KCODES;               // 512 floats

    vq_wsum<<<KCODES / 256, 256, 0, stream>>>(weight, wsum);
    vq_main<<<NBLOCKS, BLOCK, 0, stream>>>(inp, weight, wsum,
                                           out_q, out_idx, block_loss);
    vq_loss_reduce<<<1, BLOCK, 0, stream>>>(block_loss, out_loss);
}

// Round 4
// 406.012 us; speedup vs baseline: 1.1809x; 1.1809x over previous
//
#include <hip/hip_runtime.h>
#include <math.h>

// Problem constants
#define N_ROWS   131072      // 32*64*64 pixels
#define DIM      64          // embedding dim
#define KCODES   1024        // codebook entries
#define HWSZ     4096        // 64*64
#define CHW      262144      // 64*64*64 (per-batch NCHW stride)
#define OUT_ELEMS 8388608    // 32*64*64*64
#define BLOCK    256
#define NBLOCKS  (N_ROWS / BLOCK)   // 512  -> exactly 2 blocks/CU
#define TILE_K   256         // codes per LDS tile (64 KB); 2 blocks/CU fit in 160 KB

// ---------------------------------------------------------------------------
// numpy pairwise sum of squares, n=64 (8-accumulator block, scalar order).
// Bit-exact np.sum(v**2, axis=-1); contract(off) keeps mul/add separate.
// ---------------------------------------------------------------------------
__device__ __forceinline__ float np_sumsq64(const float* v) {
#pragma clang fp contract(off)
    float r[8];
#pragma unroll
    for (int j = 0; j < 8; ++j) r[j] = v[j] * v[j];
#pragma unroll
    for (int i = 8; i < 64; i += 8) {
#pragma unroll
        for (int j = 0; j < 8; ++j) {
            float p = v[i + j] * v[i + j];
            r[j] = r[j] + p;
        }
    }
    float s01 = r[0] + r[1];
    float s23 = r[2] + r[3];
    float s45 = r[4] + r[5];
    float s67 = r[6] + r[7];
    return (s01 + s23) + (s45 + s67);
}

// ---------------------------------------------------------------------------
// Kernel 0: per-code ||w_k||^2 (numpy-pairwise) -> ws[0..1023]
// ---------------------------------------------------------------------------
__global__ __launch_bounds__(256) void vq_wsum(const float* __restrict__ w,
                                               float* __restrict__ wsum) {
    int k = blockIdx.x * blockDim.x + threadIdx.x;   // grid = 4*256 = 1024
    const float* wr = w + k * DIM;
    float wv[DIM];
#pragma unroll
    for (int d = 0; d < DIM; ++d) wv[d] = wr[d];
    wsum[k] = np_sumsq64(wv);
}

// ---------------------------------------------------------------------------
// Kernel 1: main VQ. One thread per pixel/row; x[64] in VGPRs.
//   Weights staged in 64KB LDS tiles; all lanes read the same w address
//   (broadcast ds_read, conflict-free) so the VALU never waits on SMEM.
//   k-unroll x2 = 2 independent fmaf chains/thread for dep-latency cover.
//   Numerics BIT-IDENTICAL to the round-3 passing kernel:
//     a  = np_sumsq64(x)
//     c  = sequential __builtin_fmaf chain d=0..63
//     dk = fl( fl(a+b_k) - 2*c ),  argmin strict < (dk0 before dk1)
// ---------------------------------------------------------------------------
__global__ __launch_bounds__(256, 2) void vq_main(const float* __restrict__ inp,
                                                  const float* __restrict__ weight,
                                                  const float* __restrict__ wsum,
                                                  float* __restrict__ out,
                                                  float* __restrict__ idx_out,
                                                  float* __restrict__ block_loss) {
    __shared__ float sw[TILE_K * DIM];   // 64 KB weight tile
    __shared__ float sws[TILE_K];        // 1 KB  wsum tile
    __shared__ float red[BLOCK / 64];

    const int tid = threadIdx.x;
    const int n  = blockIdx.x * BLOCK + tid;   // grid exact: 512*256
    const int b  = n >> 12;            // n / 4096
    const int hw = n & 4095;           // n % 4096

    const float* xbase = inp + (size_t)b * CHW + hw;
    float x[DIM];
#pragma unroll
    for (int d = 0; d < DIM; ++d) x[d] = xbase[(size_t)d * HWSZ];

    const float a = np_sumsq64(x);

    float best  = 3.402823466e38f;
    int   bestk = 0;

    for (int tile = 0; tile < KCODES; tile += TILE_K) {
        // ---- stage tile: 256 codes x 64 floats, coalesced float4 loads ----
        __syncthreads();   // protect previous tile's readers
        {
            const float4* gsrc = (const float4*)(weight + (size_t)tile * DIM);
            float4* ldst = (float4*)sw;
            // 16384 floats = 4096 float4; 256 threads -> 16 each
#pragma unroll
            for (int i = 0; i < 16; ++i)
                ldst[i * BLOCK + tid] = gsrc[i * BLOCK + tid];
            sws[tid] = wsum[tile + tid];
        }
        __syncthreads();

        // ---- sweep tile: 2 codes per iteration (2 independent chains) ----
        for (int kk = 0; kk < TILE_K; kk += 2) {
            const float* w0 = &sw[kk * DIM];
            const float* w1 = &sw[(kk + 1) * DIM];
            float c0 = 0.f, c1 = 0.f;
#pragma unroll
            for (int d = 0; d < DIM; ++d) {
                c0 = __builtin_fmaf(x[d], w0[d], c0);
                c1 = __builtin_fmaf(x[d], w1[d], c1);
            }
            float s0, dk0, s1, dk1;
            {
#pragma clang fp contract(off)
                s0  = a + sws[kk];
                dk0 = s0 - 2.0f * c0;
                s1  = a + sws[kk + 1];
                dk1 = s1 - 2.0f * c1;
            }
            const int k0 = tile + kk;
            if (dk0 < best) { best = dk0; bestk = k0; }
            if (dk1 < best) { best = dk1; bestk = k0 + 1; }
        }
    }

    // Epilogue: gather winning code row, write out (coalesced), loss partial.
    const float* wbest = weight + bestk * DIM;   // per-lane gather, L2-hot
    float* obase = out + (size_t)b * CHW + hw;
    float  ls = 0.f;
#pragma unroll
    for (int c = 0; c < DIM; ++c) {
        const float wv = wbest[c];
        obase[(size_t)c * HWSZ] = wv;
        const float df = wv - x[c];
        ls = fmaf(df, df, ls);
    }
    idx_out[n] = (float)bestk;

    // Block reduction of loss partial (4 waves of 64)
#pragma unroll
    for (int off = 32; off > 0; off >>= 1) ls += __shfl_down(ls, off, 64);
    const int lane = tid & 63;
    const int wid  = tid >> 6;
    if (lane == 0) red[wid] = ls;
    __syncthreads();
    if (tid == 0)
        block_loss[blockIdx.x] = (red[0] + red[1]) + (red[2] + red[3]);
}

// ---------------------------------------------------------------------------
// Kernel 2: reduce 512 block partials -> loss scalar
//   loss = q + 0.25*e = 1.25 * mean((quantized - x)^2)
// ---------------------------------------------------------------------------
__global__ __launch_bounds__(256) void vq_loss_reduce(const float* __restrict__ bl,
                                                      float* __restrict__ loss_out) {
    double s = 0.0;
    for (int i = threadIdx.x; i < NBLOCKS; i += BLOCK) s += (double)bl[i];
    __shared__ double red[BLOCK / 64];
#pragma unroll
    for (int off = 32; off > 0; off >>= 1) s += __shfl_down(s, off, 64);
    const int lane = threadIdx.x & 63;
    const int wid  = threadIdx.x >> 6;
    if (lane == 0) red[wid] = s;
    __syncthreads();
    if (threadIdx.x == 0) {
        const double total = (red[0] + red[1]) + (red[2] + red[3]);
        loss_out[0] = (float)(1.25 * total / (double)OUT_ELEMS);
    }
}

// ---------------------------------------------------------------------------
extern "C" void kernel_launch(void* const* d_in, const int* in_sizes, int n_in,
                              void* d_out, int out_size, void* d_ws, size_t ws_size,
                              hipStream_t stream) {
    const float* inp    = (const float*)d_in[0];   // [32,64,64,64] NCHW fp32
    const float* weight = (const float*)d_in[1];   // [1024,64] fp32

    float* out_q    = (float*)d_out;                         // 8388608 elems
    float* out_loss = (float*)d_out + OUT_ELEMS;             // 1 elem
    float* out_idx  = (float*)d_out + OUT_ELEMS + 1;         // 131072 elems

    float* wsum       = (float*)d_ws;                        // 1024 floats
    float* block_loss = (float*)d_ws + KCODES;               // 512 floats

    vq_wsum<<<KCODES / 256, 256, 0, stream>>>(weight, wsum);
    vq_main<<<NBLOCKS, BLOCK, 0, stream>>>(inp, weight, wsum,
                                           out_q, out_idx, block_loss);
    vq_loss_reduce<<<1, BLOCK, 0, stream>>>(block_loss, out_loss);
}